// Round 13
// baseline (319.941 us; speedup 1.0000x reference)
//
#include <hip/hip_runtime.h>
#include <hip/hip_bf16.h>

// Problem constants
#define CIN_   26
#define HIN_   721
#define WIN_   1440
#define K_     9
#define HOUT_  360
#define KH_    9
#define KW_    9
#define COUT_  256
#define WOUT_  720

#define WT     16                 // w-tile per block (720/16 = 45 tiles)
#define XSP    42                 // xs row pitch in u16 (84 B = 21 banks, gcd(21,32)=1)
#define CK     (CIN_ * K_)        // 234  (== CIN_*KH_, rows of xs)
#define KPAD   256                // phase-2 K padded (8 k-steps of 32)
#define ACCP   264                // u16 pitch: 528B rows, 16B aligned
#define NMT    (COUT_ / 16)       // 16 m-tiles
#define NKS    (KPAD / 32)        // 8 k-steps
#define NXCD   8
#define HBAND  (HOUT_ / NXCD)     // 45 h-rows per XCD band

typedef short bf16x8 __attribute__((ext_vector_type(8)));
typedef float f32x4  __attribute__((ext_vector_type(4)));

// Fragment-ordered bf16 weight: [(mt*NKS+ks)*64 + lane]*8 + j   (128 KB)
__device__ unsigned short g_whi[NMT * NKS * 64 * 8];
// Per-h psi A-fragments for phase 1: [(h*3 + ks)*64 + lane]*8 + e  (1.1 MB)
__device__ unsigned short g_pfrag[HOUT_ * 3 * 64 * 8];

__device__ __forceinline__ unsigned short f2bf_rne(float f) {
    union { float f; unsigned u; } v; v.f = f;
    unsigned u = v.u;
    unsigned r = (u + 0x7FFFu + ((u >> 16) & 1u)) >> 16;
    return (unsigned short)r;
}

// A-operand layout for mfma_f32_16x16x32_bf16: row m = lane&15, k = ks*32 + (lane>>4)*8 + j
__global__ void prep_weight_kernel(const float* __restrict__ weight) {
    const int bid  = blockIdx.x;        // 0..127  (mt*NKS + ks)
    const int mt   = bid / NKS;
    const int ks   = bid % NKS;
    const int lane = threadIdx.x;       // 0..63
    const int m    = mt * 16 + (lane & 15);
    const int k0   = ks * 32 + (lane >> 4) * 8;
    const int base = ((mt * NKS + ks) * 64 + lane) * 8;
    #pragma unroll
    for (int j = 0; j < 8; ++j) {
        const int k = k0 + j;
        const float w = (k < CK) ? weight[m * CK + k] : 0.f;
        g_whi[base + j] = f2bf_rne(w);
    }
}

// Phase-1 contraction ordering over the 81 (dh,dw) taps, padded to 96:
//   slot s in [0,72):  dh = s>>3, dw = s&7    (adjacent-dw pairs -> b32 reads)
//   slot s in [72,81): dh = s-72, dw = 8      (the dw=8 singles)
//   slot s in [81,96): zero padding
// A-fragment (psi) per h: row m = lane&15 (psi k), slot s = ks*32 + (lane>>4)*8 + e
__global__ void prep_psi_kernel(const float* __restrict__ psi) {
    const int h    = blockIdx.x;        // 0..359
    const int lane = threadIdx.x;       // 0..63
    const int m    = lane & 15;
    const int kg   = lane >> 4;
    #pragma unroll
    for (int ks = 0; ks < 3; ++ks) {
        const int base = ((h * 3 + ks) * 64 + lane) * 8;
        #pragma unroll
        for (int e = 0; e < 8; ++e) {
            const int s = ks * 32 + kg * 8 + e;
            float v = 0.f;
            if (m < 9) {
                if (s < 72)      v = psi[(m * HOUT_ + h) * 81 + (s >> 3) * 9 + (s & 7)];
                else if (s < 81) v = psi[(m * HOUT_ + h) * 81 + (s - 72) * 9 + 8];
            }
            g_pfrag[base + e] = f2bf_rne(v);
        }
    }
}

__global__ __launch_bounds__(256, 5)
void disco_fused_kernel(const float* __restrict__ x,
                        const int*   __restrict__ hi_base,
                        float* __restrict__ out)
{
    __shared__ unsigned short xs_bf[CK][XSP];                 // 234*42*2 = 19656 B
    __shared__ __align__(16) unsigned short acc_s[WT][ACCP];  //  8448 B
                                                              // total 28104 B -> 5 blocks/CU

    const int b    = blockIdx.x;        // 0..16199
    const int xcd  = b & (NXCD - 1);
    const int jb   = b >> 3;            // 0..2024
    const int h    = xcd * HBAND + jb / 45;
    const int tile = jb % 45;
    const int w0   = tile * WT;
    const int tid  = threadIdx.x;

    const int hib = hi_base[h];         // in [0, 716]

    // ---- zero acc_s k-padding region [224,256) (phase 1 later overwrites 224..233) ----
    #pragma unroll
    for (int t = 0; t < 2; ++t) {
        const int idx = tid + t * 256;  // 0..511
        acc_s[idx >> 5][224 + (idx & 31)] = 0;
    }

    // ---- stage x tile as bf16: row-per-thread, float2 pair loads ----
    // cols 0..39 cover w-taps (max used col = 2*15+8 = 38); pairs never straddle
    // the mod-1440 wrap because c0 and 1440 are both even.
    const int c0 = 2 * w0 - 4;          // in [-4, 1404]
    if (tid < CK) {
        const int dh = tid % KH_;
        const int c  = tid / KH_;
        int r = hib + dh;
        if (r > HIN_ - 1) r = HIN_ - 1;
        const float* xrow = x + ((size_t)c * HIN_ + r) * WIN_;
        unsigned short* dst = &xs_bf[tid][0];
        #pragma unroll 4
        for (int j = 0; j < 20; ++j) {
            int g = c0 + 2 * j;
            if (g < 0)          g += WIN_;
            else if (g >= WIN_) g -= WIN_;
            const float2 v = *reinterpret_cast<const float2*>(xrow + g);
            const __hip_bfloat162 bv = __float22bfloat162_rn(v);
            *reinterpret_cast<unsigned*>(dst + 2 * j) = *reinterpret_cast<const unsigned*>(&bv);
        }
    }

    const int lane = tid & 63;
    const int wid  = tid >> 6;          // 4 waves
    const int n    = lane & 15;
    const int kg   = lane >> 4;

    // ---- load psi A-fragments (precomputed, coalesced 16B/lane) ----
    bf16x8 afrag[3];
    #pragma unroll
    for (int ks = 0; ks < 3; ++ks)
        afrag[ks] = *(const bf16x8*)&g_pfrag[((h * 3 + ks) * 64 + lane) * 8];

    __syncthreads();

    // ---- phase 1: acc[(c,k)][w] via MFMA, psi as A, xs as B ----
    const char* xsb = (const char*)&xs_bf[0][0];
    for (int c = wid; c < CIN_; c += 4) {
        const int base = c * (KH_ * XSP * 2) + 4 * n;   // byte offset: c*756 + 4n
        f32x4 C = {0.f, 0.f, 0.f, 0.f};
        #pragma unroll
        for (int ks = 0; ks < 3; ++ks) {
            union { bf16x8 v; unsigned d[4]; unsigned short u[8]; } bf;
            if (ks < 2 || kg == 0) {
                // all-pairs: dh = ks*4 + kg (group-uniform), dwords t -> cols (2n+2t, 2n+2t+1)
                const int dh = ks * 4 + kg;
                const char* p = xsb + base + dh * (XSP * 2);
                #pragma unroll
                for (int t = 0; t < 4; ++t)
                    bf.d[t] = *(const unsigned*)(p + 4 * t);
            } else if (kg == 1) {
                // singles s = 72..79: dh = e, dw = 8 -> byte = e*84 + 4n + 16
                #pragma unroll
                for (int e = 0; e < 8; ++e)
                    bf.u[e] = *(const unsigned short*)(xsb + base + e * (XSP * 2) + 16);
            } else if (kg == 2) {
                bf.d[0] = bf.d[1] = bf.d[2] = bf.d[3] = 0;
                bf.u[0] = *(const unsigned short*)(xsb + base + 8 * (XSP * 2) + 16);  // s=80: dh=8,dw=8
            } else {
                bf.d[0] = bf.d[1] = bf.d[2] = bf.d[3] = 0;
            }
            C = __builtin_amdgcn_mfma_f32_16x16x32_bf16(afrag[ks], bf.v, C, 0, 0, 0);
        }
        // C row m = kg*4 + r (psi k), col n = w  ->  acc_s[n][c*9 + m]
        #pragma unroll
        for (int r = 0; r < 4; ++r) {
            const int m = kg * 4 + r;
            if (m < 9) acc_s[n][c * 9 + m] = f2bf_rne(C[r]);
        }
    }
    __syncthreads();

    // ---- phase 2: C[256x16] = W[256xK] * acc[Kx16] via bf16 MFMA ----
    f32x4 C0 = {0.f, 0.f, 0.f, 0.f};
    f32x4 C1 = C0, C2 = C0, C3 = C0;

    for (int ks = 0; ks < NKS; ++ks) {
        const int kof = ks * 32 + kg * 8;             // multiple of 8 -> 16B aligned
        const bf16x8 bhi = *(const bf16x8*)&acc_s[n][kof];

        #pragma unroll
        for (int i = 0; i < 4; ++i) {
            const int mt    = wid * 4 + i;
            const int abase = ((mt * NKS + ks) * 64 + lane) * 8;
            const bf16x8 ahi = *(const bf16x8*)&g_whi[abase];
            f32x4 acc = (i == 0) ? C0 : (i == 1) ? C1 : (i == 2) ? C2 : C3;
            acc = __builtin_amdgcn_mfma_f32_16x16x32_bf16(ahi, bhi, acc, 0, 0, 0);
            if (i == 0) C0 = acc; else if (i == 1) C1 = acc; else if (i == 2) C2 = acc; else C3 = acc;
        }
    }

    // ---- epilogue: D layout col = lane&15, row = (lane>>4)*4 + reg ----
    #pragma unroll
    for (int i = 0; i < 4; ++i) {
        const f32x4 acc = (i == 0) ? C0 : (i == 1) ? C1 : (i == 2) ? C2 : C3;
        const int m0 = (wid * 4 + i) * 16 + kg * 4;
        #pragma unroll
        for (int r = 0; r < 4; ++r) {
            out[(size_t)(m0 + r) * (HOUT_ * WOUT_) + h * WOUT_ + w0 + n] = acc[r];
        }
    }
}

extern "C" void kernel_launch(void* const* d_in, const int* in_sizes, int n_in,
                              void* d_out, int out_size, void* d_ws, size_t ws_size,
                              hipStream_t stream)
{
    const float* x       = (const float*)d_in[0];
    const float* psi     = (const float*)d_in[1];
    const float* weight  = (const float*)d_in[2];
    const int*   hi_base = (const int*)d_in[3];
    float* out = (float*)d_out;

    hipLaunchKernelGGL(prep_weight_kernel, dim3(NMT * NKS), dim3(64), 0, stream, weight);
    hipLaunchKernelGGL(prep_psi_kernel,    dim3(HOUT_),     dim3(64), 0, stream, psi);

    dim3 grid(45 * HOUT_, 1, 1);   // 16200, 1-D for XCD swizzle
    dim3 block(256, 1, 1);
    hipLaunchKernelGGL(disco_fused_kernel, grid, block, 0, stream,
                       x, hi_base, out);
}